// Round 6
// baseline (1296.339 us; speedup 1.0000x reference)
//
#include <hip/hip_runtime.h>
#include <stdint.h>
#include <stddef.h>

#define B_ 4
#define C_ 256
#define T_ 128
#define NB_ 64
#define NF_ 512
#define PLAT_ (T_*NB_)    // 8192
#define PSIDE_ (T_*NF_)   // 65536

using bf16x8 = __attribute__((ext_vector_type(8))) short;
using bf16x4 = __attribute__((ext_vector_type(4))) short;
using f32x4  = __attribute__((ext_vector_type(4))) float;

__device__ __forceinline__ float b2f(unsigned short h) {
  unsigned int u = ((unsigned int)h) << 16;
  return __builtin_bit_cast(float, u);
}
__device__ __forceinline__ float b2f(short h) {
  unsigned int u = ((unsigned int)(unsigned short)h) << 16;
  return __builtin_bit_cast(float, u);
}
__device__ __forceinline__ unsigned short f2b(float f) {
  unsigned int u = __builtin_bit_cast(unsigned int, f);
  u += 0x7FFFu + ((u >> 16) & 1u);
  return (unsigned short)(u >> 16);
}

__device__ __forceinline__ bf16x8 ld8(const unsigned short* p) {
  return *(const bf16x8*)p;
}
__device__ __forceinline__ bf16x8 ld8(const float* p) {
  float4 a = *(const float4*)p;
  float4 b = *(const float4*)(p + 4);
  bf16x8 r;
  r[0] = (short)f2b(a.x); r[1] = (short)f2b(a.y);
  r[2] = (short)f2b(a.z); r[3] = (short)f2b(a.w);
  r[4] = (short)f2b(b.x); r[5] = (short)f2b(b.y);
  r[6] = (short)f2b(b.z); r[7] = (short)f2b(b.w);
  return r;
}
__device__ __forceinline__ void stv(float* p, float v) { *p = v; }
__device__ __forceinline__ void stv(unsigned short* p, float v) { *p = f2b(v); }

// async global->LDS, 16B per lane; lds dst must be wave-uniform base (lane*16 added by HW)
__device__ __forceinline__ void gload16(const void* g, void* l) {
  __builtin_amdgcn_global_load_lds(
      (const __attribute__((address_space(1))) void*)g,
      (__attribute__((address_space(3))) void*)l, 16, 0, 0);
}

// chunk-XOR swizzle selector for 4x16B rows; u4i(r + 128k) == u4i(r)
__device__ __forceinline__ int u4i(int r) { return (r ^ (r >> 2)) & 3; }

enum { EPI_NONE = 0, EPI_SILU = 1, EPI_RESID = 3, EPI_SWIGLU = 4, EPI_DUALX = 5 };

// fold per-channel norm weight into conv weight (fp32 in, bf16 out)
__global__ __launch_bounds__(256) void wprep_k(const float* __restrict__ w,
                                               const float* __restrict__ nw,
                                               unsigned short* __restrict__ out, int n)
{
  int i = blockIdx.x * 256 + threadIdx.x;
  if (i < n) out[i] = f2b(w[i] * nw[i & 255]);
}

// plain fp32 -> bf16 convert
__global__ __launch_bounds__(256) void cvt_k(const float* __restrict__ in,
                                             unsigned short* __restrict__ out, int n)
{
  int i = blockIdx.x * 256 + threadIdx.x;
  if (i < n) out[i] = f2b(in[i]);
}

// scaled convert: out[i] = bf16(w[i] * s[0])
__global__ __launch_bounds__(256) void wscale_k(const float* __restrict__ w,
                                                const float* __restrict__ s,
                                                unsigned short* __restrict__ out, int n)
{
  int i = blockIdx.x * 256 + threadIdx.x;
  if (i < n) out[i] = f2b(w[i] * s[0]);
}

// weight fold: out[m][c] = bf16( sum_j A[m][j] * Bm[j][c] )  (q_w @ qmlp_out)
__global__ __launch_bounds__(256) void foldw_k(const float* __restrict__ A,
                                               const float* __restrict__ Bm,
                                               unsigned short* __restrict__ out)
{
  const int m = blockIdx.x;
  const int c = threadIdx.x;
  float acc = 0.f;
  #pragma unroll 8
  for (int j = 0; j < C_; ++j) acc = fmaf(A[m * C_ + j], Bm[j * C_ + c], acc);
  out[m * C_ + c] = f2b(acc);
}

// bias fold: bout[m] = sum_j A[m][j]*bin[j] + badd[m]
__global__ __launch_bounds__(256) void foldb_k(const float* __restrict__ A,
                                               const float* __restrict__ bin,
                                               const float* __restrict__ badd,
                                               float* __restrict__ bout)
{
  const int m = threadIdx.x;
  float acc = 0.f;
  #pragma unroll 8
  for (int j = 0; j < C_; ++j) acc = fmaf(A[m * C_ + j], bin[j], acc);
  bout[m] = acc + badd[m];
}

// bias combine: bout[m] = b0[m] + s[0]*b1[m]
__global__ __launch_bounds__(256) void bcomb_k(const float* __restrict__ b0,
                                               const float* __restrict__ b1,
                                               const float* __restrict__ s,
                                               float* __restrict__ bout)
{
  const int m = threadIdx.x;
  bout[m] = b0[m] + s[0] * b1[m];
}

// -------------------------------------------------------------------------
// Transpose+convert: X fp32 [z][C][Xs] -> XT bf16 [z][pix-local][C], plus
// per-pixel RMS scale PS[z][pix-local] = rsqrt(mean_c x^2 + eps) from fp32.
// Block = 64 pixels x 256 channels. LDS sT rows = pixel (512B, 32 chunks of
// 16B), chunk swizzled ch' = ch ^ (p&31): conflict-free b128 writes+reads.
__global__ __launch_bounds__(256) void xpose_k(
    const float* __restrict__ X, unsigned short* __restrict__ XT,
    float* __restrict__ PS, int Xs, int Xoff, int Pl)
{
  __shared__ unsigned short sT[64 * 256];
  __shared__ float red[4][64];
  const int tid = threadIdx.x;
  const int lane = tid & 63;
  const int wid = tid >> 6;
  const int z = blockIdx.z;
  const int p0 = blockIdx.x * 64;
  const float* Xb = X + (size_t)z * C_ * Xs + Xoff + p0;

  float sq = 0.f;
  #pragma unroll
  for (int kt = 0; kt < 8; ++kt) {
    const float* xp = Xb + (size_t)(kt * 32 + wid * 8) * Xs + lane;
    float v[8];
    #pragma unroll
    for (int j = 0; j < 8; ++j) v[j] = xp[(size_t)j * Xs];
    bf16x8 w8;
    #pragma unroll
    for (int j = 0; j < 8; ++j) { sq = fmaf(v[j], v[j], sq); w8[j] = (short)f2b(v[j]); }
    const int ch = kt * 4 + wid;
    *(bf16x8*)(&sT[lane * 256 + ((ch ^ (lane & 31)) << 3)]) = w8;
  }
  red[wid][lane] = sq;
  __syncthreads();
  if (tid < 64)
    PS[(size_t)z * Pl + p0 + tid] =
        rsqrtf((red[0][tid] + red[1][tid] + red[2][tid] + red[3][tid]) * (1.0f / (float)C_) + 1e-6f);
  #pragma unroll
  for (int it = 0; it < 8; ++it) {
    const int p = it * 8 + (tid >> 5);
    const int ch = tid & 31;
    bf16x8 val = *(const bf16x8*)(&sT[p * 256 + ((ch ^ (p & 31)) << 3)]);
    *(bf16x8*)(&XT[((size_t)z * Pl + p0 + p) * C_ + ch * 8]) = val;
  }
}

// -------------------------------------------------------------------------
// GEMM over channels, tall-M blocks (no m-redundancy on X reads).
// CFG 0: BM=256, grid.x = strips of BN, 4 waves on M.
// CFG 1: BM=128, grid.x = 2*strips (paired: m-half = bx&1, adjacent dispatch
//        -> X strip L2-hits), 2x2 waves.
// BN in {64,128}: pixel-strip width (wave N = BN/NWV).
// X layouts:
//  XT=true : X bf16 transposed [z][pix][C_] -> global_load_lds, source-swizzled
//  XT=false: X fp32 [z][C_][Xs] (BN==64 only) -> k-major per-thread loads,
//            pack bf16x8, one ds_write_b128. RMS fused via per-pixel sumsq.
// EPI_SWIGLU: dual W banks + dual acc -> a*silu(g); CSIN applies pscale col-scale.
// EPI_DUALX : dual W banks + dual X, single acc; writes hidden bf16T (YT) and
//             per-pixel RMS scale to pscale (norm deferred to consumer). BN=64.
// EPI_RESID : Y = acc + bias + bf16T-residual RT (final fp32 out, no RMW).
template<int EPI, bool RMS, bool XT, typename TY, bool YT, int CFG, bool CSIN, int BN>
__global__ __launch_bounds__(256, 2) void gemm_k(
    const void* __restrict__ Xv,
    const void* __restrict__ Xv2,
    const unsigned short* __restrict__ W,
    const float* __restrict__ bias,
    TY* Y,
    const unsigned short* __restrict__ RT,
    float* pscale,
    int Xs, int Xoff, int Ys, int Yoff, int Ps)
{
  constexpr bool WDUAL = (EPI == EPI_SWIGLU) || (EPI == EPI_DUALX);
  constexpr bool GDUAL = (EPI == EPI_SWIGLU);
  constexpr bool XDUAL = (EPI == EPI_DUALX);
  constexpr int BM  = (CFG == 0) ? 256 : 128;
  constexpr int NWV = (CFG == 0) ? 1 : 2;       // waves on N
  constexpr int WN  = BN / NWV;                 // wave N width
  constexpr int NFR = WN / 16;                  // n-frags per wave
  constexpr int RW  = (WDUAL ? 2 : 1) * BM;     // sA rows
  constexpr int XR  = (XDUAL ? 2 : 1) * BN;     // sX rows

  __shared__ unsigned short sA[RW * 32];
  __shared__ unsigned short sX[XR * 32];
  __shared__ float red[4][BN];

  const int tid = threadIdx.x;
  const int lane = tid & 63;
  const int wid = tid >> 6;
  const int l15 = lane & 15;
  const int q4 = lane >> 4;
  const int z = blockIdx.z;
  const int p0 = ((CFG == 0) ? blockIdx.x : (blockIdx.x >> 1)) * BN;
  const int m0 = (CFG == 0) ? 0 : (blockIdx.x & 1) * BM;
  const int mh = (CFG == 0) ? wid : (wid >> 1);
  const int nh = (CFG == 0) ? 0 : (wid & 1);

  const float* Xf = nullptr;
  const unsigned short* Xt = nullptr;
  const unsigned short* Xt2 = nullptr;
  if constexpr (XT) {
    Xt = (const unsigned short*)Xv + ((size_t)z * Xs + Xoff + p0) * C_;
    if constexpr (XDUAL)
      Xt2 = (const unsigned short*)Xv2 + ((size_t)z * Xs + Xoff + p0) * C_;
  } else {
    Xf = (const float*)Xv + (size_t)z * C_ * Xs + Xoff + p0;
  }

  const f32x4 zf = {0.f, 0.f, 0.f, 0.f};
  f32x4 acc0[4][NFR];
  f32x4 acc1[GDUAL ? 4 : 1][GDUAL ? NFR : 1];
  #pragma unroll
  for (int i = 0; i < 4; ++i)
    #pragma unroll
    for (int j = 0; j < NFR; ++j) {
      acc0[i][j] = zf;
      if constexpr (GDUAL) acc1[i][j] = zf;
    }

  float sq = 0.f;   // fp32-path per-pixel sumsq partial (pixel = lane)

  for (int kt = 0; kt < 8; ++kt) {
    // ---- stage X ----
    if constexpr (XT) {
      #pragma unroll
      for (int j2 = 0; j2 < BN / 64; ++j2) {
        const int rbase = wid * (BN / 4) + j2 * 16;
        const int row = rbase + (lane >> 2);
        const int chunk = (lane & 3) ^ u4i(row);
        const size_t soff = (size_t)row * C_ + kt * 32 + (chunk << 3);
        gload16(Xt + soff, &sX[rbase * 32]);
        if constexpr (XDUAL) gload16(Xt2 + soff, &sX[(BN + rbase) * 32]);
      }
    } else {
      // BN == 64 only
      const float* xp = Xf + (size_t)(kt * 32 + wid * 8) * Xs + lane;
      float v[8];
      #pragma unroll
      for (int j = 0; j < 8; ++j) v[j] = xp[(size_t)j * Xs];
      bf16x8 w8;
      #pragma unroll
      for (int j = 0; j < 8; ++j) {
        if constexpr (RMS) sq = fmaf(v[j], v[j], sq);
        w8[j] = (short)f2b(v[j]);
      }
      *(bf16x8*)((char*)sX + lane * 64 + ((wid ^ u4i(lane)) << 4)) = w8;
    }
    // ---- stage W (global_load_lds, source-swizzled) ----
    #pragma unroll
    for (int it = 0; it < RW / 64; ++it) {
      const int rbase = wid * (RW / 4) + it * 16;
      const int rl = rbase + (lane >> 2);
      const int bank = rl / BM;
      const int rloc = rl & (BM - 1);
      const int chunk = (lane & 3) ^ u4i(rl);
      gload16(W + (size_t)(bank * C_ + m0 + rloc) * C_ + kt * 32 + (chunk << 3),
              &sA[rbase * 32]);
    }
    __syncthreads();

    // ---- fragments + MFMA ----
    bf16x8 af0[4], af1[4], bfr[NFR], bfr2[NFR];
    #pragma unroll
    for (int mf = 0; mf < 4; ++mf) {
      const int r = mh * 64 + mf * 16 + l15;
      const int sl = (q4 ^ u4i(r)) << 3;
      af0[mf] = *(const bf16x8*)(&sA[r * 32 + sl]);
      if constexpr (WDUAL) af1[mf] = *(const bf16x8*)(&sA[(BM + r) * 32 + sl]);
    }
    #pragma unroll
    for (int nf = 0; nf < NFR; ++nf) {
      const int n = nh * WN + nf * 16 + l15;
      const int sl = (q4 ^ u4i(n)) << 3;
      bfr[nf] = *(const bf16x8*)(&sX[n * 32 + sl]);
      if constexpr (XDUAL) bfr2[nf] = *(const bf16x8*)(&sX[(BN + n) * 32 + sl]);
    }
    #pragma unroll
    for (int mf = 0; mf < 4; ++mf)
      #pragma unroll
      for (int nf = 0; nf < NFR; ++nf) {
        acc0[mf][nf] = __builtin_amdgcn_mfma_f32_16x16x32_bf16(af0[mf], bfr[nf], acc0[mf][nf], 0, 0, 0);
        if constexpr (GDUAL)
          acc1[mf][nf] = __builtin_amdgcn_mfma_f32_16x16x32_bf16(af1[mf], bfr[nf], acc1[mf][nf], 0, 0, 0);
        if constexpr (XDUAL)
          acc0[mf][nf] = __builtin_amdgcn_mfma_f32_16x16x32_bf16(af1[mf], bfr2[nf], acc0[mf][nf], 0, 0, 0);
      }
    __syncthreads();
  }

  // ---- column scales ----
  float cs[NFR];
  #pragma unroll
  for (int nf = 0; nf < NFR; ++nf) cs[nf] = 1.f;
  if constexpr (RMS) {
    red[wid][lane] = sq;
    __syncthreads();
    #pragma unroll
    for (int nf = 0; nf < NFR; ++nf) {
      const int n = nh * WN + nf * 16 + l15;
      cs[nf] = rsqrtf((red[0][n] + red[1][n] + red[2][n] + red[3][n]) * (1.0f / (float)C_) + 1e-6f);
    }
  }
  if constexpr (CSIN) {
    #pragma unroll
    for (int nf = 0; nf < NFR; ++nf)
      cs[nf] = pscale[(size_t)z * Ps + p0 + nh * WN + nf * 16 + l15];
  }

  // ---- epilogue ----
  TY* Yb = nullptr;
  if constexpr (!YT) Yb = Y + (size_t)z * C_ * Ys + Yoff;

  float p2[NFR];
  #pragma unroll
  for (int nf = 0; nf < NFR; ++nf) p2[nf] = 0.f;

  #pragma unroll
  for (int mf = 0; mf < 4; ++mf) {
    const int mb = m0 + mh * 64 + mf * 16 + q4 * 4;
    const float4 b1 = *(const float4*)(bias + mb);
    float4 b2 = {0.f, 0.f, 0.f, 0.f};
    if constexpr (GDUAL) b2 = *(const float4*)(bias + C_ + mb);
    #pragma unroll
    for (int nf = 0; nf < NFR; ++nf) {
      const int pl = p0 + nh * WN + nf * 16 + l15;
      bf16x4 h4 = {0, 0, 0, 0};
      if constexpr (EPI == EPI_RESID)
        h4 = *(const bf16x4*)(RT + ((size_t)z * Ps + pl) * C_ + mb);
      if constexpr (YT) {
        bf16x4 pk;
        #pragma unroll
        for (int r = 0; r < 4; ++r) {
          float y = acc0[mf][nf][r] * cs[nf] + ((const float*)&b1)[r];
          if constexpr (EPI == EPI_SILU) y = y / (1.0f + __expf(-y));
          if constexpr (EPI == EPI_SWIGLU) {
            float g = acc1[mf][nf][r] * cs[nf] + ((const float*)&b2)[r];
            y = y * (g / (1.0f + __expf(-g)));
          }
          if constexpr (EPI == EPI_DUALX) p2[nf] = fmaf(y, y, p2[nf]);
          pk[r] = (short)f2b(y);
        }
        *(bf16x4*)(Y + ((size_t)z * Ys + Yoff + pl) * C_ + mb) = pk;
      } else {
        #pragma unroll
        for (int r = 0; r < 4; ++r) {
          const size_t oidx = (size_t)(mb + r) * Ys + pl;
          float y = acc0[mf][nf][r] * cs[nf] + ((const float*)&b1)[r];
          if constexpr (EPI == EPI_SILU) y = y / (1.0f + __expf(-y));
          if constexpr (EPI == EPI_SWIGLU) {
            float g = acc1[mf][nf][r] * cs[nf] + ((const float*)&b2)[r];
            y = y * (g / (1.0f + __expf(-g)));
          }
          if constexpr (EPI == EPI_RESID) y += b2f(h4[r]);
          stv(&Yb[oidx], y);
        }
      }
    }
  }

  // ---- DUALX tail: per-pixel RMS scale of hidden -> pscale (BN=64, CFG0) ----
  if constexpr (EPI == EPI_DUALX) {
    #pragma unroll
    for (int nf = 0; nf < NFR; ++nf) {
      p2[nf] += __shfl_xor(p2[nf], 16);
      p2[nf] += __shfl_xor(p2[nf], 32);
    }
    if (q4 == 0) {
      #pragma unroll
      for (int nf = 0; nf < NFR; ++nf) red[wid][nf * 16 + l15] = p2[nf];
    }
    __syncthreads();
    if (wid == 0 && q4 == 0) {
      #pragma unroll
      for (int nf = 0; nf < NFR; ++nf) {
        const int n = nf * 16 + l15;
        const float c2 = rsqrtf((red[0][n] + red[1][n] + red[2][n] + red[3][n]) * (1.0f / (float)C_) + 1e-6f);
        pscale[(size_t)z * Ps + p0 + n] = c2;
      }
    }
  }
}

// -------------------------------------------------------------------------
// Fused cross-attention, one block per (z, t_local).
// Q, K transposed bf16 [pix][C_]; V non-transposed [C_][pix]; O transposed (in-place on Q buf).
// sK/sQ: linear [64][256] with 8-way chunk XOR: slot s of row n holds chunk s ^ (n&7).
__global__ __launch_bounds__(256) void attn_k(
    const unsigned short* Q,
    const unsigned short* __restrict__ Kp,
    const unsigned short* __restrict__ Vp,
    const float* __restrict__ basis,
    const float* __restrict__ ssp,
    const float* __restrict__ psp,
    unsigned short* O,
    int PsQ, int t0, int ltc)
{
  __shared__ unsigned short sK[64 * 256];
  __shared__ unsigned short sQ[64 * 256];
  __shared__ unsigned short sV[256 * 72];   // [c][n] (A-operand)
  __shared__ unsigned short sW[64 * 72];    // [f][n] softmax weights (B-operand)
  __shared__ unsigned short sB[64 * 72];    // [n][f] bias chunk

  const int tid = threadIdx.x;
  const int lane = tid & 63;
  const int wid = tid >> 6;
  const int l15 = lane & 15;
  const int q4 = lane >> 4;
  const int z = blockIdx.x >> ltc;
  const int tl = blockIdx.x & ((1 << ltc) - 1);

  const unsigned short* Qt = Q + ((size_t)z * PsQ + (size_t)tl * NF_) * C_;
  unsigned short*       Ot = O + ((size_t)z * PsQ + (size_t)tl * NF_) * C_;
  const unsigned short* Kt = Kp + ((size_t)z * PLAT_ + (size_t)(t0 + tl) * NB_) * C_;
  const size_t vbase = (size_t)z * C_ * PLAT_ + (size_t)(t0 + tl) * NB_;

  const float ss = ssp[0];
  const float ps = psp[0];
  const f32x4 zf = {0.f, 0.f, 0.f, 0.f};

  // stage K (gload_lds, swizzled) and V (reg path) once per block
  {
    #pragma unroll
    for (int it = 0; it < 8; ++it) {
      int i = wid * 8 + it;
      int n = 2 * i + (lane >> 5);
      int sc = (lane & 31) ^ (n & 7);
      gload16(Kt + (size_t)n * C_ + (sc << 3), &sK[i * 512]);
    }
    const int c0 = tid >> 3;
    const int n0 = (tid & 7) << 3;
    #pragma unroll
    for (int pass = 0; pass < 8; ++pass) {
      int c = c0 + pass * 32;
      bf16x8 v8 = *(const bf16x8*)(Vp + vbase + (size_t)c * PLAT_ + n0);
      *(bf16x8*)(&sV[c * 72 + n0]) = v8;
    }
  }

  for (int fc = 0; fc < 8; ++fc) {
    const int f0 = fc * 64;
    // stage Q chunk (gload_lds, swizzled) and fp32 bias chunk [n][f]
    #pragma unroll
    for (int it = 0; it < 8; ++it) {
      int i = wid * 8 + it;
      int n = 2 * i + (lane >> 5);
      int sc = (lane & 31) ^ (n & 7);
      gload16(Qt + (size_t)(f0 + n) * C_ + (sc << 3), &sQ[i * 512]);
    }
    {
      const int nr = tid >> 3;
      const int fl0 = (tid & 7) << 3;
      #pragma unroll
      for (int pass = 0; pass < 2; ++pass) {
        int nn = nr + pass * 32;
        bf16x8 b8 = ld8(basis + (size_t)nn * NF_ + f0 + fl0);
        *(bf16x8*)(&sB[nn * 72 + fl0]) = b8;
      }
    }
    __syncthreads();

    // scores: wave wid owns f rows [wid*16, wid*16+16)
    f32x4 sacc[4];
    #pragma unroll
    for (int nt = 0; nt < 4; ++nt) sacc[nt] = zf;
    const int frow = wid * 16 + l15;
    const int swq = l15 & 7;
    #pragma unroll
    for (int kt = 0; kt < 8; ++kt) {
      int kb = kt * 4 + q4;
      bf16x8 a8 = *(const bf16x8*)(&sQ[frow * 256 + ((kb ^ swq) << 3)]);
      #pragma unroll
      for (int nt = 0; nt < 4; ++nt) {
        bf16x8 b8 = *(const bf16x8*)(&sK[(nt * 16 + l15) * 256 + ((kb ^ swq) << 3)]);
        sacc[nt] = __builtin_amdgcn_mfma_f32_16x16x32_bf16(a8, b8, sacc[nt], 0, 0, 0);
      }
    }

    // softmax over n=64
    #pragma unroll
    for (int r = 0; r < 4; ++r) {
      const int fcl = wid * 16 + q4 * 4 + r;
      float v[4];
      #pragma unroll
      for (int nt = 0; nt < 4; ++nt)
        v[nt] = sacc[nt][r] * ss + b2f(sB[(nt * 16 + l15) * 72 + fcl]) * ps;
      float mx = fmaxf(fmaxf(v[0], v[1]), fmaxf(v[2], v[3]));
      #pragma unroll
      for (int d = 1; d < 16; d <<= 1) mx = fmaxf(mx, __shfl_xor(mx, d));
      float e[4], sum = 0.f;
      #pragma unroll
      for (int nt = 0; nt < 4; ++nt) { e[nt] = __expf(v[nt] - mx); sum += e[nt]; }
      #pragma unroll
      for (int d = 1; d < 16; d <<= 1) sum += __shfl_xor(sum, d);
      float inv = 1.0f / sum;
      #pragma unroll
      for (int nt = 0; nt < 4; ++nt)
        sW[fcl * 72 + nt * 16 + l15] = f2b(e[nt] * inv);
    }
    __syncthreads();

    // PV: wave wid owns c rows [wid*64, wid*64+64)
    f32x4 pacc[4][4];
    #pragma unroll
    for (int mf = 0; mf < 4; ++mf)
      #pragma unroll
      for (int nf = 0; nf < 4; ++nf) pacc[mf][nf] = zf;
    #pragma unroll
    for (int kt = 0; kt < 2; ++kt) {
      int k0 = kt * 32 + q4 * 8;
      bf16x8 a8[4], b8[4];
      #pragma unroll
      for (int mf = 0; mf < 4; ++mf)
        a8[mf] = *(const bf16x8*)(&sV[(wid * 64 + mf * 16 + l15) * 72 + k0]);
      #pragma unroll
      for (int nf = 0; nf < 4; ++nf)
        b8[nf] = *(const bf16x8*)(&sW[(nf * 16 + l15) * 72 + k0]);
      #pragma unroll
      for (int mf = 0; mf < 4; ++mf)
        #pragma unroll
        for (int nf = 0; nf < 4; ++nf)
          pacc[mf][nf] = __builtin_amdgcn_mfma_f32_16x16x32_bf16(a8[mf], b8[nf], pacc[mf][nf], 0, 0, 0);
    }
    // O write, transposed [f][c], 8B per store
    #pragma unroll
    for (int mf = 0; mf < 4; ++mf) {
      int cb = wid * 64 + mf * 16 + q4 * 4;
      #pragma unroll
      for (int nf = 0; nf < 4; ++nf) {
        int f = f0 + nf * 16 + l15;
        bf16x4 pk;
        #pragma unroll
        for (int r = 0; r < 4; ++r) pk[r] = (short)f2b(pacc[mf][nf][r]);
        *(bf16x4*)(Ot + (size_t)f * C_ + cb) = pk;
      }
    }
    __syncthreads();
  }
}

// -------------------------------------------------------------------------
extern "C" void kernel_launch(void* const* d_in, const int* in_sizes, int n_in,
                              void* d_out, int out_size, void* d_ws, size_t ws_size,
                              hipStream_t stream)
{
  (void)in_sizes; (void)n_in; (void)out_size;
  const float* latent     = (const float*)d_in[0];
  const float* side       = (const float*)d_in[1];
  const float* basis      = (const float*)d_in[2];
  const float* lp_norm_w  = (const float*)d_in[3];
  const float* lp_w       = (const float*)d_in[4];
  const float* lp_b       = (const float*)d_in[5];
  const float* qn_w       = (const float*)d_in[6];
  const float* qmlp_in_w  = (const float*)d_in[7];
  const float* qmlp_in_b  = (const float*)d_in[8];
  const float* qmlp_out_w = (const float*)d_in[9];
  const float* qmlp_out_b = (const float*)d_in[10];
  const float* q_w        = (const float*)d_in[11];
  const float* q_b        = (const float*)d_in[12];
  const float* k_w        = (const float*)d_in[13];
  const float* k_b        = (const float*)d_in[14];
  const float* v_w        = (const float*)d_in[15];
  const float* v_b        = (const float*)d_in[16];
  const float* o_w        = (const float*)d_in[17];
  const float* o_b        = (const float*)d_in[18];
  const float* ffn_norm_w = (const float*)d_in[19];
  const float* ffn_in_w   = (const float*)d_in[20];
  const float* ffn_in_b   = (const float*)d_in[21];
  const float* ffn_out_w  = (const float*)d_in[22];
  const float* ffn_out_b  = (const float*)d_in[23];
  const float* sc_scale   = (const float*)d_in[24];
  const float* pr_scale   = (const float*)d_in[25];
  const float* qk_scale   = (const float*)d_in[26];
  float* out = (float*)d_out;

  // ---- workspace carve, chunk count chosen to FIT ws_size ----
  // fixed: 5x(C*C bf16) + 3x(2C*C bf16) + 2x(C fp32) + 3x(B*C*PLAT bf16)
  // per-chunk: 3x(B*C*Pc bf16) + 2x(B*Pc fp32)
  auto align256 = [](size_t b) { return (b + 255) & ~(size_t)255; };
  const size_t fixed_bytes =
      5 * align256((size_t)C_ * C_ * 2) +
      3 * align256((size_t)2 * C_ * C_ * 2) +
      2 * align256((size_t)C_ * 4) +
      3 * align256((size_t)B_ * C_ * PLAT_ * 2);
  int nc = 16;
  for (int c = 1; c <= 16; c <<= 1) {
    size_t Pcb = (size_t)PSIDE_ / c;
    size_t need = fixed_bytes + 3 * align256((size_t)B_ * C_ * Pcb * 2)
                + 2 * align256((size_t)B_ * Pcb * 4);
    if (need <= ws_size) { nc = c; break; }
  }
  const int Pc  = PSIDE_ / nc;
  const int Tc  = T_ / nc;
  int ltc = 0; while ((1 << ltc) < Tc) ++ltc;   // log2(Tc)

  char* ws = (char*)d_ws;
  size_t off = 0;
  auto carve = [&](size_t bytes) -> char* {
    char* p = ws + off;
    off += (bytes + 255) & ~(size_t)255;
    return p;
  };
  unsigned short* wlp      = (unsigned short*)carve((size_t)C_ * C_ * 2);
  unsigned short* wqin     = (unsigned short*)carve((size_t)2 * C_ * C_ * 2);
  unsigned short* wffin    = (unsigned short*)carve((size_t)2 * C_ * C_ * 2);
  unsigned short* wk       = (unsigned short*)carve((size_t)C_ * C_ * 2);
  unsigned short* wv       = (unsigned short*)carve((size_t)C_ * C_ * 2);
  unsigned short* wfo      = (unsigned short*)carve((size_t)C_ * C_ * 2);
  unsigned short* wqeff    = (unsigned short*)carve((size_t)C_ * C_ * 2);
  unsigned short* wocat    = (unsigned short*)carve((size_t)2 * C_ * C_ * 2);  // [o_w ; qss*qmlp_out_w]
  float*          beff     = (float*)carve((size_t)C_ * 4);
  float*          bcomb    = (float*)carve((size_t)C_ * 4);
  unsigned short* latent_h = (unsigned short*)carve((size_t)B_ * C_ * PLAT_ * 2);
  unsigned short* kbuf     = (unsigned short*)carve((size_t)B_ * C_ * PLAT_ * 2);
  unsigned short* vbuf     = (unsigned short*)carve((size_t)B_ * C_ * PLAT_ * 2);
  unsigned short* big0     = (unsigned short*)carve((size_t)B_ * C_ * Pc * 2);
  unsigned short* qbuf     = (unsigned short*)carve((size_t)B_ * C_ * Pc * 2);
  unsigned short* sideT    = (unsigned short*)carve((size_t)B_ * C_ * Pc * 2);
  float*          pscale   = (float*)carve((size_t)B_ * Pc * 4);
  float*          spscale  = (float*)carve((size_t)B_ * Pc * 4);

  const dim3 blk(256);
  const dim3 gLat64(PLAT_ / 64, 1, B_);
  const dim3 gLat128(PLAT_ / 128, 1, B_);
  const dim3 gCh64(Pc / 64, 1, B_);
  const dim3 gCh128(Pc / 128, 1, B_);
  const dim3 gChB(Pc / 128 * 2, 1, B_);   // CFG1 BN=128: paired W-halves
  const int NW = C_ * C_;   // 65536

  // weight prep
  wprep_k<<<dim3(NW / 256), blk, 0, stream>>>(lp_w, lp_norm_w, wlp, NW);
  wprep_k<<<dim3(2 * NW / 256), blk, 0, stream>>>(qmlp_in_w, qn_w, wqin, 2 * NW);
  wprep_k<<<dim3(2 * NW / 256), blk, 0, stream>>>(ffn_in_w, ffn_norm_w, wffin, 2 * NW);
  cvt_k<<<dim3(NW / 256), blk, 0, stream>>>(k_w, wk, NW);
  cvt_k<<<dim3(NW / 256), blk, 0, stream>>>(v_w, wv, NW);
  cvt_k<<<dim3(NW / 256), blk, 0, stream>>>(ffn_out_w, wfo, NW);
  foldw_k<<<dim3(C_), blk, 0, stream>>>(q_w, qmlp_out_w, wqeff);
  foldb_k<<<dim3(1), blk, 0, stream>>>(q_w, qmlp_out_b, q_b, beff);
  cvt_k<<<dim3(NW / 256), blk, 0, stream>>>(o_w, wocat, NW);
  wscale_k<<<dim3(NW / 256), blk, 0, stream>>>(qmlp_out_w, qk_scale, wocat + (size_t)NW, NW);
  bcomb_k<<<dim3(1), blk, 0, stream>>>(o_b, qmlp_out_b, qk_scale, bcomb);

  // latent path (once): rms fused into lp-gemm (fp32 path, BN=64)
  gemm_k<EPI_SILU, true, false, unsigned short, true, 0, false, 64><<<gLat64, blk, 0, stream>>>(
      latent, nullptr, wlp, lp_b, latent_h, nullptr, nullptr, PLAT_, 0, PLAT_, 0, 0);
  gemm_k<EPI_NONE, false, true, unsigned short, true, 0, false, 128><<<gLat128, blk, 0, stream>>>(
      latent_h, nullptr, wk, k_b, kbuf, nullptr, nullptr, PLAT_, 0, PLAT_, 0, 0);
  gemm_k<EPI_NONE, false, true, unsigned short, false, 0, false, 128><<<gLat128, blk, 0, stream>>>(
      latent_h, nullptr, wv, v_b, vbuf, nullptr, nullptr, PLAT_, 0, PLAT_, 0, 0);

  // side path, chunked over t
  for (int ch = 0; ch < nc; ++ch) {
    const int co = ch * Pc;
    const int t0 = ch * Tc;
    // sideT = bf16T(side chunk); spscale = per-pixel rms scale (fp32-exact)
    xpose_k<<<gCh64, blk, 0, stream>>>(side, sideT, spscale, PSIDE_, co, Pc);
    // big0 = swiglu_inner(qmlp_in @ side) * spscale-normed  [XT fast path]
    gemm_k<EPI_SWIGLU, false, true, unsigned short, true, 1, true, 128><<<gChB, blk, 0, stream>>>(
        sideT, nullptr, wqin, qmlp_in_b, big0, nullptr, spscale, Pc, 0, Pc, 0, Pc);
    // qbuf = (q_w @ qmlp_out) @ big0 + folded bias
    gemm_k<EPI_NONE, false, true, unsigned short, true, 0, false, 128><<<gCh128, blk, 0, stream>>>(
        big0, nullptr, wqeff, beff, qbuf, nullptr, nullptr, Pc, 0, Pc, 0, 0);
    // attention in-place over qbuf
    attn_k<<<dim3(B_ * Tc), blk, 0, stream>>>(qbuf, kbuf, vbuf, basis, sc_scale, pr_scale,
                                              qbuf, Pc, t0, ltc);
    // hidden = o_w @ attended + qss*(qmlp_out @ big0) + comb_bias
    //   -> qbuf (bf16T, in-place, UNNORMED) + pscale (per-pixel rms scale)
    gemm_k<EPI_DUALX, false, true, unsigned short, true, 0, false, 64><<<gCh64, blk, 0, stream>>>(
        qbuf, big0, wocat, bcomb, qbuf, nullptr, pscale, Pc, 0, Pc, 0, Pc);
    // FFN in: reads unnormed hiddenT, applies norm as column scale (CSIN)
    gemm_k<EPI_SWIGLU, false, true, unsigned short, true, 1, true, 128><<<gChB, blk, 0, stream>>>(
        qbuf, nullptr, wffin, ffn_in_b, big0, nullptr, pscale, Pc, 0, Pc, 0, Pc);
    // out = wfo @ big0 + ffn_out_b + hiddenT  (single fp32 write, no RMW)
    gemm_k<EPI_RESID, false, true, float, false, 0, false, 128><<<gCh128, blk, 0, stream>>>(
        big0, nullptr, wfo, ffn_out_b, out, qbuf, nullptr, Pc, 0, PSIDE_, co, Pc);
  }
}